// Round 10
// baseline (100.331 us; speedup 1.0000x reference)
//
#include <hip/hip_runtime.h>
#include <hip/hip_bf16.h>
#include <math.h>

#define N_CLASS 200000
#define DIM     192
#define BATCH   64
#define NSLOT   3
#define M_ROWS  192            // B*N
#define GRID_M  512            // k_main blocks: 2 per CU
// class tiles of 32: 6250 = 512*12 + 106

#define S_SCALE 30.0f
#define COS_M   0.9800665778412416f
#define SIN_M   0.19866933079506122f
#define TH_C    (-0.9800665778412416f)
#define MM_C    0.039733866159012245f

typedef __attribute__((ext_vector_type(8))) short bf16x8;
typedef __attribute__((ext_vector_type(4))) float f32x4;

__device__ __forceinline__ float wave_reduce_sum(float v) {
#pragma unroll
    for (int o = 32; o > 0; o >>= 1) v += __shfl_xor(v, o, 64);
    return v;
}

__device__ __forceinline__ unsigned short f2bf(float f) {
    union { __hip_bfloat16 h; unsigned short u; } v;
    v.h = __float2bfloat16(f);
    return v.u;
}

__device__ __forceinline__ bf16x8 pack8(float4 a, float4 b) {
    bf16x8 r;
    r[0] = (short)f2bf(a.x); r[1] = (short)f2bf(a.y);
    r[2] = (short)f2bf(a.z); r[3] = (short)f2bf(a.w);
    r[4] = (short)f2bf(b.x); r[5] = (short)f2bf(b.y);
    r[6] = (short)f2bf(b.z); r[7] = (short)f2bf(b.w);
    return r;
}

// ---- normalize pred_embs -> xn fp32 [row][k] and xbf bf16 [row][k] ----
__global__ void k_normalize(const float* __restrict__ pe,
                            float* __restrict__ xn, unsigned short* __restrict__ xbf) {
    int r = blockIdx.x;      // 0..191
    int l = threadIdx.x;     // 0..63
    float v0 = pe[r * DIM + l];
    float v1 = pe[r * DIM + l + 64];
    float v2 = pe[r * DIM + l + 128];
    float ss = wave_reduce_sum(v0 * v0 + v1 * v1 + v2 * v2);
    float rn = 1.0f / fmaxf(sqrtf(ss), 1e-6f);
    float a0 = v0 * rn, a1 = v1 * rn, a2 = v2 * rn;
    xn[r * DIM + l]       = a0;
    xn[r * DIM + l + 64]  = a1;
    xn[r * DIM + l + 128] = a2;
    xbf[r * DIM + l]       = f2bf(a0);
    xbf[r * DIM + l + 64]  = f2bf(a1);
    xbf[r * DIM + l + 128] = f2bf(a2);
}

// ---- gt-label cosines in exact fp32 ----
__global__ void k_gtcos(const float* __restrict__ weight, const int* __restrict__ gt,
                        const float* __restrict__ xn, float* __restrict__ cosl) {
    int i = blockIdx.x;             // b*S + s
    int b = i / NSLOT, s = i - b * NSLOT;
    int l = threadIdx.x;
    int lab = gt[b * NSLOT + s];
    const float* w = weight + (long)lab * DIM;
    float w0 = w[l], w1 = w[l + 64], w2 = w[l + 128];
    float ss = wave_reduce_sum(w0 * w0 + w1 * w1 + w2 * w2);
    float rn = 1.0f / fmaxf(sqrtf(ss), 1e-6f);
    for (int n = 0; n < NSLOT; ++n) {
        const float* x = xn + (b * NSLOT + n) * DIM;
        float d = wave_reduce_sum(w0 * x[l] + w1 * x[l + 64] + w2 * x[l + 128]);
        float c = fminf(fmaxf(d * rn, -1.0f + 1e-7f), 1.0f - 1e-7f);
        if (l == 0) cosl[(b * NSLOT + n) * NSLOT + s] = c;
    }
}

// ---- MFMA GEMM: A in registers, W DIRECT to registers, NO hot-loop LDS ----
// 512 threads = 8 waves = 2 class-groups(16) x 4 row-groups(48 rows).
// No __syncthreads/vmcnt coupling in the loop: each wave streams its own
// W classes with independent dwordx4 loads; compiler-inserted per-wave
// waitcnt + 16 waves/CU TLP hide latency (m114 regime). Raw s_barrier
// (execution-only, no data dep) keeps the 4 rg-waves L1-aligned.
__global__ __launch_bounds__(512, 4)
void k_main(const float* __restrict__ weight,
            const unsigned short* __restrict__ xbf,
            float* __restrict__ partials) {
    __shared__ float red[M_ROWS * 2];   // 1.5 KB, epilogue only

    const int tid  = threadIdx.x;
    const int lane = tid & 63;
    const int wid  = tid >> 6;      // 0..7
    const int cg   = wid & 1;       // class group (16 classes)
    const int rg   = wid >> 1;      // row group (48 rows)
    const int lr   = lane & 15;
    const int q    = lane >> 4;     // k-quad
    const int bid  = blockIdx.x;

    const int ntile = 12 + (bid < 106 ? 1 : 0);   // 6250 = 512*12 + 106

    // ---- A fragments straight from global (once): row rg*48+t*16+lr, k s*32+q*8
    bf16x8 areg[3][6];
#pragma unroll
    for (int t = 0; t < 3; ++t) {
        const unsigned short* xp = xbf + (rg * 48 + t * 16 + lr) * DIM + q * 8;
#pragma unroll
        for (int s = 0; s < 6; ++s)
            areg[t][s] = *reinterpret_cast<const bf16x8*>(xp + s * 32);
    }

    f32x4 acc[3];
#pragma unroll
    for (int t = 0; t < 3; ++t) acc[t] = (f32x4){0.f, 0.f, 0.f, 0.f};
    float rs[3][4];
#pragma unroll
    for (int t = 0; t < 3; ++t)
#pragma unroll
        for (int r = 0; r < 4; ++r) rs[t][r] = 0.f;

    // my class row for tile j: (bid + j*GRID_M)*32 + cg*16 + lr
    const float* wp = weight + ((long)bid * 32 + cg * 16 + lr) * DIM + q * 8;
    const long tstep = (long)GRID_M * 32 * DIM;

#pragma unroll 1
    for (int j = 0; j < ntile; ++j) {
        __builtin_amdgcn_s_barrier();   // exec-only sync (no memory dep): L1 alignment
        float sq = 0.f;
#pragma unroll
        for (int s = 0; s < 6; ++s) {
            float4 wv1 = *reinterpret_cast<const float4*>(wp + s * 32);
            float4 wv2 = *reinterpret_cast<const float4*>(wp + s * 32 + 4);
            sq += wv1.x*wv1.x + wv1.y*wv1.y + wv1.z*wv1.z + wv1.w*wv1.w
                + wv2.x*wv2.x + wv2.y*wv2.y + wv2.z*wv2.z + wv2.w*wv2.w;
            bf16x8 bb = pack8(wv1, wv2);
            acc[0] = __builtin_amdgcn_mfma_f32_16x16x32_bf16(areg[0][s], bb, acc[0], 0, 0, 0);
            acc[1] = __builtin_amdgcn_mfma_f32_16x16x32_bf16(areg[1][s], bb, acc[1], 0, 0, 0);
            acc[2] = __builtin_amdgcn_mfma_f32_16x16x32_bf16(areg[2][s], bb, acc[2], 0, 0, 0);
        }
        wp += tstep;
        // ---- per-tile epilogue: class norm + exp accumulation ----
        float s2 = sq;
        s2 += __shfl_xor(s2, 16); s2 += __shfl_xor(s2, 32);
        float rn = 1.0f / fmaxf(sqrtf(s2), 1e-6f);
#pragma unroll
        for (int t = 0; t < 3; ++t)
#pragma unroll
            for (int r = 0; r < 4; ++r) {
                float c = fminf(fmaxf(acc[t][r] * rn, -1.0f + 1e-7f), 1.0f - 1e-7f);
                rs[t][r] += __expf(S_SCALE * c - 30.0f);   // exp(30c-30) <= 1
                acc[t][r] = 0.f;
            }
    }

    // ---- block epilogue: reduce across 16 classes (lr), combine 2 cg via LDS ----
#pragma unroll
    for (int t = 0; t < 3; ++t)
#pragma unroll
        for (int r = 0; r < 4; ++r) {
            float v = rs[t][r];
            v += __shfl_xor(v, 1); v += __shfl_xor(v, 2);
            v += __shfl_xor(v, 4); v += __shfl_xor(v, 8);
            rs[t][r] = v;
        }
    if (lr == 0) {
#pragma unroll
        for (int t = 0; t < 3; ++t)
#pragma unroll
            for (int r = 0; r < 4; ++r)
                red[(rg * 48 + t * 16 + q * 4 + r) * 2 + cg] = rs[t][r];
    }
    __syncthreads();
    if (tid < M_ROWS)
        partials[(long)bid * M_ROWS + tid] = red[tid * 2] + red[tid * 2 + 1];
}

// ---- deterministic reduce over 512 block partials per row ----
__global__ void k_reduce(const float* __restrict__ partials, float* __restrict__ sum_exp) {
    int r = blockIdx.x;              // 0..191
    float s = 0.0f;
    for (int i = threadIdx.x; i < GRID_M; i += 256)
        s += partials[(long)i * M_ROWS + r];
    s = wave_reduce_sum(s);
    __shared__ float wsm[4];
    int wid = threadIdx.x >> 6;
    if ((threadIdx.x & 63) == 0) wsm[wid] = s;
    __syncthreads();
    if (threadIdx.x == 0) sum_exp[r] = wsm[0] + wsm[1] + wsm[2] + wsm[3];
}

// ---- ce matrix, permutation argmin, final losses ----
__global__ void k_final(const float* __restrict__ sum_exp, const float* __restrict__ cosl,
                        const float* __restrict__ pred_ps, float* __restrict__ out) {
    int b = threadIdx.x;  // 0..63, one wave
    const int perms[6][3] = {{0,1,2},{0,2,1},{1,0,2},{1,2,0},{2,0,1},{2,1,0}};
    float ce[3][3];  // [n][s]
#pragma unroll
    for (int n = 0; n < 3; ++n) {
        float lse = 30.0f + logf(sum_exp[b * 3 + n]);
#pragma unroll
        for (int s = 0; s < 3; ++s) {
            float c  = cosl[(b * 3 + n) * 3 + s];
            float sl = sqrtf(fmaxf(1.0f - c * c, 1e-7f));
            float phi = c * COS_M - sl * SIN_M;
            phi = (c > TH_C) ? phi : (c - MM_C);
            float lm = lse + log1pf(expf(S_SCALE * phi - lse) - expf(S_SCALE * c - lse));
            ce[n][s] = lm - S_SCALE * phi;
        }
    }
    float best = 1e30f;
    int bp = 0;
#pragma unroll
    for (int p = 0; p < 6; ++p) {
        float cost = ce[perms[p][0]][0] + ce[perms[p][1]][1] + ce[perms[p][2]][2];
        if (cost < best) { best = cost; bp = p; }
    }
    float lspk = (ce[perms[bp][0]][0] + ce[perms[bp][1]][1] + ce[perms[bp][2]][2]) / 3.0f;

    float p0 = fminf(fmaxf(pred_ps[b * 4 + 0], 1e-6f), 1.0f - 1e-6f);
    float p1 = fminf(fmaxf(pred_ps[b * 4 + 1], 1e-6f), 1.0f - 1e-6f);
    float p2 = fminf(fmaxf(pred_ps[b * 4 + 2], 1e-6f), 1.0f - 1e-6f);
    float p3 = fminf(fmaxf(pred_ps[b * 4 + 3], 1e-6f), 1.0f - 1e-6f);
    float lcnt = -(log1pf(-p0) + log1pf(-p1) + log1pf(-p2) + logf(p3)) * 0.25f;

    float ts  = wave_reduce_sum(lspk) / 64.0f;
    float tcn = wave_reduce_sum(lcnt) / 64.0f;
    if (b == 0) {
        out[0] = ts + 0.1f * tcn;
        out[1] = ts;
        out[2] = tcn;
    }
}

extern "C" void kernel_launch(void* const* d_in, const int* in_sizes, int n_in,
                              void* d_out, int out_size, void* d_ws, size_t ws_size,
                              hipStream_t stream) {
    const float* pred_embs = (const float*)d_in[0];
    const float* pred_ps   = (const float*)d_in[1];
    const int*   gt_labels = (const int*)d_in[2];
    const float* weight    = (const float*)d_in[3];
    float* out = (float*)d_out;
    char*  ws  = (char*)d_ws;

    float*          xn       = (float*)(ws);                   // 147456 B
    unsigned short* xbf      = (unsigned short*)(ws + 147456); // 73728 B
    float*          cosl     = (float*)(ws + 221184);          // 2304 B
    float*          sum_exp  = (float*)(ws + 223488);          // 768 B
    float*          partials = (float*)(ws + 224256);          // 512*192*4 B

    k_normalize<<<M_ROWS, 64, 0, stream>>>(pred_embs, xn, xbf);
    k_main<<<GRID_M, 512, 0, stream>>>(weight, xbf, partials);
    k_gtcos<<<BATCH * NSLOT, 64, 0, stream>>>(weight, gt_labels, xn, cosl);
    k_reduce<<<M_ROWS, 256, 0, stream>>>(partials, sum_exp);
    k_final<<<1, 64, 0, stream>>>(sum_exp, cosl, pred_ps, out);
}

// Round 11
// 88.377 us; speedup vs baseline: 1.1353x; 1.1353x over previous
//
#include <hip/hip_runtime.h>
#include <hip/hip_bf16.h>
#include <math.h>

#define N_CLASS 200000
#define DIM     192
#define BATCH   64
#define NSLOT   3
#define M_ROWS  192            // B*N
#define GRID_M  1024           // k_main blocks
#define NTILE   6250           // class-tiles of 32

#define S_SCALE 30.0f
#define COS_M   0.9800665778412416f
#define SIN_M   0.19866933079506122f
#define TH_C    (-0.9800665778412416f)
#define MM_C    0.039733866159012245f

typedef __attribute__((ext_vector_type(8))) short bf16x8;
typedef __attribute__((ext_vector_type(4))) float f32x4;

__device__ __forceinline__ float wave_reduce_sum(float v) {
#pragma unroll
    for (int o = 32; o > 0; o >>= 1) v += __shfl_xor(v, o, 64);
    return v;
}

__device__ __forceinline__ unsigned short f2bf(float f) {
    union { __hip_bfloat16 h; unsigned short u; } v;
    v.h = __float2bfloat16(f);
    return v.u;
}

__device__ __forceinline__ bf16x8 pack8(float4 a, float4 b) {
    bf16x8 r;
    r[0] = (short)f2bf(a.x); r[1] = (short)f2bf(a.y);
    r[2] = (short)f2bf(a.z); r[3] = (short)f2bf(a.w);
    r[4] = (short)f2bf(b.x); r[5] = (short)f2bf(b.y);
    r[6] = (short)f2bf(b.z); r[7] = (short)f2bf(b.w);
    return r;
}

// ---- normalize pred_embs -> xn fp32 [row][k] and xbf bf16 [row][k] ----
__global__ void k_normalize(const float* __restrict__ pe,
                            float* __restrict__ xn, unsigned short* __restrict__ xbf) {
    int r = blockIdx.x;      // 0..191
    int l = threadIdx.x;     // 0..63
    float v0 = pe[r * DIM + l];
    float v1 = pe[r * DIM + l + 64];
    float v2 = pe[r * DIM + l + 128];
    float ss = wave_reduce_sum(v0 * v0 + v1 * v1 + v2 * v2);
    float rn = 1.0f / fmaxf(sqrtf(ss), 1e-6f);
    float a0 = v0 * rn, a1 = v1 * rn, a2 = v2 * rn;
    xn[r * DIM + l]       = a0;
    xn[r * DIM + l + 64]  = a1;
    xn[r * DIM + l + 128] = a2;
    xbf[r * DIM + l]       = f2bf(a0);
    xbf[r * DIM + l + 64]  = f2bf(a1);
    xbf[r * DIM + l + 128] = f2bf(a2);
}

// ---- gt-label cosines in exact fp32 ----
__global__ void k_gtcos(const float* __restrict__ weight, const int* __restrict__ gt,
                        const float* __restrict__ xn, float* __restrict__ cosl) {
    int i = blockIdx.x;             // b*S + s
    int b = i / NSLOT, s = i - b * NSLOT;
    int l = threadIdx.x;
    int lab = gt[b * NSLOT + s];
    const float* w = weight + (long)lab * DIM;
    float w0 = w[l], w1 = w[l + 64], w2 = w[l + 128];
    float ss = wave_reduce_sum(w0 * w0 + w1 * w1 + w2 * w2);
    float rn = 1.0f / fmaxf(sqrtf(ss), 1e-6f);
    for (int n = 0; n < NSLOT; ++n) {
        const float* x = xn + (b * NSLOT + n) * DIM;
        float d = wave_reduce_sum(w0 * x[l] + w1 * x[l + 64] + w2 * x[l + 128]);
        float c = fminf(fmaxf(d * rn, -1.0f + 1e-7f), 1.0f - 1e-7f);
        if (l == 0) cosl[(b * NSLOT + n) * NSLOT + s] = c;
    }
}

// ---- pack: W fp32 row-major -> normalized bf16, MFMA-fragment-ordered ----
// Block = 256 thr, handles 2 class-tiles of 32. Coalesced f4 reads -> LDS
// (chunk-XOR swizzled), per-class rsqrt(sumsq) fused, fragment writes are
// fully coalesced 1-KB wave stores.
// Layout: wpack[((tile*12 + cg*6 + s)*512) + lane*8] shorts, lane=(q<<4)|lr,
// holding w_hat[tile*32+cg*16+lr][s*32+q*8 .. +7].
__global__ __launch_bounds__(256) void k_pack(const float* __restrict__ weight,
                                              unsigned short* __restrict__ wpack) {
    __shared__ __align__(16) float ws32[32 * DIM];  // 24 KB
    __shared__ float rnl[32];
    const int tid = threadIdx.x;
    const int w = tid >> 6, l = tid & 63;
    const int q = l >> 4, lr = l & 15;

#pragma unroll 1
    for (int h = 0; h < 2; ++h) {
        const long tile = (long)blockIdx.x * 2 + h;
        const float4* src = (const float4*)(weight + tile * 32 * DIM);
        __syncthreads();   // prior-iteration frag reads done before overwrite
#pragma unroll
        for (int i = 0; i < 6; ++i) {
            int idx = tid + i * 256;              // 0..1535 f4-chunks
            int c = idx / 48, ch = idx - c * 48;
            int sch = (ch & ~7) | ((ch & 7) ^ (c & 7));
            ((float4*)ws32)[c * 48 + sch] = src[idx];
        }
        __syncthreads();
        // per-class sumsq (order-independent over swizzled chunks)
        {
            int c = tid >> 3, t8 = tid & 7;
            float s = 0.f;
#pragma unroll
            for (int i = 0; i < 6; ++i) {
                float4 v = ((const float4*)ws32)[c * 48 + t8 * 6 + i];
                s += v.x * v.x + v.y * v.y + v.z * v.z + v.w * v.w;
            }
            s += __shfl_xor(s, 1); s += __shfl_xor(s, 2); s += __shfl_xor(s, 4);
            if (t8 == 0) rnl[c] = 1.0f / fmaxf(sqrtf(s), 1e-6f);
        }
        __syncthreads();
        // fragment writes: 3 slots/thread; wave writes 1 KB contiguous
#pragma unroll
        for (int k = 0; k < 3; ++k) {
            int sl = w + k * 4;                   // 0..11
            int cg = sl & 1, s = sl >> 1;
            int c  = cg * 16 + lr;
            int ch0 = s * 8 + q * 2;
            int p0 = (ch0 & ~7) | ((ch0 & 7) ^ (c & 7));
            int p1 = ((ch0 + 1) & ~7) | (((ch0 + 1) & 7) ^ (c & 7));
            float rn = rnl[c];
            float4 a = ((const float4*)ws32)[c * 48 + p0];
            float4 b = ((const float4*)ws32)[c * 48 + p1];
            a.x *= rn; a.y *= rn; a.z *= rn; a.w *= rn;
            b.x *= rn; b.y *= rn; b.z *= rn; b.w *= rn;
            *(bf16x8*)(wpack + (tile * 12 + cg * 6 + s) * 512 + l * 8) = pack8(a, b);
        }
    }
}

// ---- MFMA GEMM: A in registers, W packed bf16, gather-free, barrier-free ----
// 512 thr = 8 waves = 2 cg x 4 rg. Per tile per wave: 6 contiguous-1KB
// bf16x8 loads + 18 MFMA + exp epilogue. No LDS / barriers in hot loop.
__global__ __launch_bounds__(512, 4)
void k_main(const unsigned short* __restrict__ wpack,
            const unsigned short* __restrict__ xbf,
            float* __restrict__ partials) {
    __shared__ float red[M_ROWS * 2];   // epilogue only

    const int tid  = threadIdx.x;
    const int lane = tid & 63;
    const int wid  = tid >> 6;      // 0..7
    const int cg   = wid & 1;       // class group (16 classes)
    const int rg   = wid >> 1;      // row group (48 rows)
    const int lr   = lane & 15;
    const int q    = lane >> 4;     // k-quad
    const int bid  = blockIdx.x;

    const int ntile = 6 + (bid < 106 ? 1 : 0);    // 6250 = 1024*6 + 106

    // A fragments from global once: row rg*48 + t*16 + lr, k s*32 + q*8
    bf16x8 areg[3][6];
#pragma unroll
    for (int t = 0; t < 3; ++t) {
        const unsigned short* xp = xbf + (rg * 48 + t * 16 + lr) * DIM + q * 8;
#pragma unroll
        for (int s = 0; s < 6; ++s)
            areg[t][s] = *reinterpret_cast<const bf16x8*>(xp + s * 32);
    }

    f32x4 acc[3];
#pragma unroll
    for (int t = 0; t < 3; ++t) acc[t] = (f32x4){0.f, 0.f, 0.f, 0.f};
    float rs[3][4];
#pragma unroll
    for (int t = 0; t < 3; ++t)
#pragma unroll
        for (int r = 0; r < 4; ++r) rs[t][r] = 0.f;

    // my fragment stream: tile j -> bid + j*GRID_M
    const unsigned short* wp = wpack + ((long)bid * 12 + (long)cg * 6) * 512 + lane * 8;
    const long tstep = (long)GRID_M * 12 * 512;

#pragma unroll 1
    for (int j = 0; j < ntile; ++j) {
#pragma unroll
        for (int s = 0; s < 6; ++s) {
            bf16x8 bb = *reinterpret_cast<const bf16x8*>(wp + s * 512);
            acc[0] = __builtin_amdgcn_mfma_f32_16x16x32_bf16(areg[0][s], bb, acc[0], 0, 0, 0);
            acc[1] = __builtin_amdgcn_mfma_f32_16x16x32_bf16(areg[1][s], bb, acc[1], 0, 0, 0);
            acc[2] = __builtin_amdgcn_mfma_f32_16x16x32_bf16(areg[2][s], bb, acc[2], 0, 0, 0);
        }
        wp += tstep;
        // epilogue: clamp + exp accumulation (norms pre-folded into wpack)
#pragma unroll
        for (int t = 0; t < 3; ++t)
#pragma unroll
            for (int r = 0; r < 4; ++r) {
                float c = fminf(fmaxf(acc[t][r], -1.0f + 1e-7f), 1.0f - 1e-7f);
                rs[t][r] += __expf(S_SCALE * c - 30.0f);   // exp(30c-30) <= 1
                acc[t][r] = 0.f;
            }
    }

    // block epilogue: reduce across 16 classes (lr), combine 2 cg via LDS
#pragma unroll
    for (int t = 0; t < 3; ++t)
#pragma unroll
        for (int r = 0; r < 4; ++r) {
            float v = rs[t][r];
            v += __shfl_xor(v, 1); v += __shfl_xor(v, 2);
            v += __shfl_xor(v, 4); v += __shfl_xor(v, 8);
            rs[t][r] = v;
        }
    if (lr == 0) {
#pragma unroll
        for (int t = 0; t < 3; ++t)
#pragma unroll
            for (int r = 0; r < 4; ++r)
                red[(rg * 48 + t * 16 + q * 4 + r) * 2 + cg] = rs[t][r];
    }
    __syncthreads();
    if (tid < M_ROWS)
        partials[(long)bid * M_ROWS + tid] = red[tid * 2] + red[tid * 2 + 1];
}

// ---- deterministic reduce over GRID_M block partials per row ----
__global__ void k_reduce(const float* __restrict__ partials, float* __restrict__ sum_exp) {
    int r = blockIdx.x;              // 0..191
    float s = 0.0f;
    for (int i = threadIdx.x; i < GRID_M; i += 256)
        s += partials[(long)i * M_ROWS + r];
    s = wave_reduce_sum(s);
    __shared__ float wsm[4];
    int wid = threadIdx.x >> 6;
    if ((threadIdx.x & 63) == 0) wsm[wid] = s;
    __syncthreads();
    if (threadIdx.x == 0) sum_exp[r] = wsm[0] + wsm[1] + wsm[2] + wsm[3];
}

// ---- ce matrix, permutation argmin, final losses ----
__global__ void k_final(const float* __restrict__ sum_exp, const float* __restrict__ cosl,
                        const float* __restrict__ pred_ps, float* __restrict__ out) {
    int b = threadIdx.x;  // 0..63, one wave
    const int perms[6][3] = {{0,1,2},{0,2,1},{1,0,2},{1,2,0},{2,0,1},{2,1,0}};
    float ce[3][3];  // [n][s]
#pragma unroll
    for (int n = 0; n < 3; ++n) {
        float lse = 30.0f + logf(sum_exp[b * 3 + n]);
#pragma unroll
        for (int s = 0; s < 3; ++s) {
            float c  = cosl[(b * 3 + n) * 3 + s];
            float sl = sqrtf(fmaxf(1.0f - c * c, 1e-7f));
            float phi = c * COS_M - sl * SIN_M;
            phi = (c > TH_C) ? phi : (c - MM_C);
            float lm = lse + log1pf(expf(S_SCALE * phi - lse) - expf(S_SCALE * c - lse));
            ce[n][s] = lm - S_SCALE * phi;
        }
    }
    float best = 1e30f;
    int bp = 0;
#pragma unroll
    for (int p = 0; p < 6; ++p) {
        float cost = ce[perms[p][0]][0] + ce[perms[p][1]][1] + ce[perms[p][2]][2];
        if (cost < best) { best = cost; bp = p; }
    }
    float lspk = (ce[perms[bp][0]][0] + ce[perms[bp][1]][1] + ce[perms[bp][2]][2]) / 3.0f;

    float p0 = fminf(fmaxf(pred_ps[b * 4 + 0], 1e-6f), 1.0f - 1e-6f);
    float p1 = fminf(fmaxf(pred_ps[b * 4 + 1], 1e-6f), 1.0f - 1e-6f);
    float p2 = fminf(fmaxf(pred_ps[b * 4 + 2], 1e-6f), 1.0f - 1e-6f);
    float p3 = fminf(fmaxf(pred_ps[b * 4 + 3], 1e-6f), 1.0f - 1e-6f);
    float lcnt = -(log1pf(-p0) + log1pf(-p1) + log1pf(-p2) + logf(p3)) * 0.25f;

    float ts  = wave_reduce_sum(lspk) / 64.0f;
    float tcn = wave_reduce_sum(lcnt) / 64.0f;
    if (b == 0) {
        out[0] = ts + 0.1f * tcn;
        out[1] = ts;
        out[2] = tcn;
    }
}

extern "C" void kernel_launch(void* const* d_in, const int* in_sizes, int n_in,
                              void* d_out, int out_size, void* d_ws, size_t ws_size,
                              hipStream_t stream) {
    const float* pred_embs = (const float*)d_in[0];
    const float* pred_ps   = (const float*)d_in[1];
    const int*   gt_labels = (const int*)d_in[2];
    const float* weight    = (const float*)d_in[3];
    float* out = (float*)d_out;
    char*  ws  = (char*)d_ws;

    float*          xn       = (float*)(ws);                   // 147456 B
    unsigned short* xbf      = (unsigned short*)(ws + 147456); // 73728 B
    float*          cosl     = (float*)(ws + 221184);          // 2304 B
    float*          sum_exp  = (float*)(ws + 223488);          // 768 B
    float*          partials = (float*)(ws + 224256);          // 1024*192*4 = 786 KB
    unsigned short* wpack    = (unsigned short*)(ws + (1 << 20)); // 76.8 MB

    k_pack<<<3125, 256, 0, stream>>>(weight, wpack);
    k_normalize<<<M_ROWS, 64, 0, stream>>>(pred_embs, xn, xbf);
    k_main<<<GRID_M, 512, 0, stream>>>(wpack, xbf, partials);
    k_gtcos<<<BATCH * NSLOT, 64, 0, stream>>>(weight, gt_labels, xn, cosl);
    k_reduce<<<M_ROWS, 256, 0, stream>>>(partials, sum_exp);
    k_final<<<1, 64, 0, stream>>>(sum_exp, cosl, pred_ps, out);
}